// Round 1
// baseline (9376.810 us; speedup 1.0000x reference)
//
#include <hip/hip_runtime.h>

// GRU: B=32, T=16384, H=64, CIN=COUT=1.
// d_out = [ out (B*T floats) | states (B*T*H floats) ], fp32.
//
// R4: latency attack on the serial scan.
//   - 12 waves (768 thr), each gate row split across 4 lanes (16 fmaf/lane,
//     dep 16cy) with DPP quad_perm xor1/xor2 combine (no LDS, ~4 VALU).
//   - raw s_barrier + lgkmcnt(0)-only drain (no vmcnt/expcnt drain of
//     __syncthreads) -> per-step global state stores are fire-and-forget.
//   - gate exchange padded to [64][4]: single ds_read_b128 post-barrier.
//   - sc staging + chunk flush + its barrier deleted.

#define Bv   32
#define Tv   16384
#define Hv   64
#define XCH  1024     // x chunk (floats)
#define NW   12       // waves
#define NT   (NW*64)  // 768 threads

__device__ __forceinline__ float dot4(float acc, const float4 a, const float4 b) {
    return fmaf(a.x, b.x, fmaf(a.y, b.y, fmaf(a.z, b.z, fmaf(a.w, b.w, acc))));
}

// v += quad_perm<CTRL>(v); 0xB1 = lanes [1,0,3,2] (xor1), 0x4E = [2,3,0,1] (xor2)
template <int CTRL>
__device__ __forceinline__ float quad_add(float v) {
    int p = __builtin_amdgcn_update_dpp(0, __float_as_int(v), CTRL, 0xF, 0xF, true);
    return v + __int_as_float(p);
}

// LDS-only barrier: drain lgkmcnt, raw s_barrier, compiler memory fences.
__device__ __forceinline__ void lds_barrier() {
    asm volatile("s_waitcnt lgkmcnt(0)" ::: "memory");
    __builtin_amdgcn_s_barrier();
    asm volatile("" ::: "memory");
}

__global__ __launch_bounds__(NT, 1) void gru_scan(
    const float* __restrict__ x,      // [B,T]
    const float* __restrict__ W_ih,   // [192] (CIN=1)
    const float* __restrict__ W_hh,   // [192,64]
    const float* __restrict__ b_ih,   // [192]
    const float* __restrict__ b_hh,   // [192]
    float* __restrict__ states)       // [B,T,64]
{
    const int b    = blockIdx.x;
    const int tid  = threadIdx.x;
    const int wv   = tid >> 6;        // wave 0..11
    const int lane = tid & 63;        // hidden unit this thread updates
    const int q    = lane & 3;        // h-quarter this lane covers (16 elems)
    const int jrow = lane >> 2;       // row within wave's 16-row strip
    const int sec  = wv >> 2;         // gate section: 0=r 1=z 2=n
    const int u    = ((wv & 3) << 4) + jrow;  // unit within section
    const int g    = (sec << 6) + u;  // global gate row 0..191

    __shared__ __align__(16) float xs[XCH];        // 4 KB x chunk
    __shared__ __align__(16) float hb[NW][Hv];     // 3 KB per-wave private h
    __shared__ __align__(16) float ghs[2][Hv][4];  // 2 KB padded gate exchange

    const float* xb = x + (size_t)b * Tv;
    float*       sb = states + (size_t)b * Tv * Hv;

    // W_hh[g, q*16 .. q*16+16) -> 4 named float4 registers
    const float4* Wv4 = reinterpret_cast<const float4*>(W_hh + (size_t)g * Hv + (q << 4));
    const float4 w0 = Wv4[0], w1 = Wv4[1], w2 = Wv4[2], w3 = Wv4[3];
    // b_hh folded into exactly one lane of the quad
    const float bhh0 = (q == 0) ? b_hh[g] : 0.0f;

    // update-phase constants (per lane; identical across all waves)
    const float wih_r = W_ih[lane];
    const float wih_z = W_ih[64  + lane];
    const float wih_n = W_ih[128 + lane];
    const float bih_r = b_ih[lane];
    const float bih_z = b_ih[64  + lane];
    const float bih_n = b_ih[128 + lane];

    hb[wv][lane] = 0.0f;   // h0 = 0, own-wave copy (same-wave DS order, no barrier)
    float h_prev = 0.0f;

    for (int t0 = 0; t0 < Tv; t0 += XCH) {
        lds_barrier();                        // prior xs readers done
        for (int i = tid; i < XCH; i += NT) xs[i] = xb[t0 + i];
        lds_barrier();                        // xs visible

#pragma unroll 2
        for (int tt = 0; tt < XCH; ++tt) {
            const int t  = t0 + tt;
            const int pb = tt & 1;

            // x-dependent gate inputs: off the post-barrier critical path
            const float xt  = xs[tt];
            const float ir  = fmaf(xt, wih_r, bih_r);
            const float iz  = fmaf(xt, wih_z, bih_z);
            const float in_ = fmaf(xt, wih_n, bih_n);

            // ---- matvec: 4 lanes per row, 16 elems each, from own-wave h ----
            const float4* hv = reinterpret_cast<const float4*>(hb[wv] + (q << 4));
            const float4 h0 = hv[0], h1 = hv[1], h2 = hv[2], h3 = hv[3];

            float a0 = bhh0, a1 = 0.0f, a2 = 0.0f, a3 = 0.0f;
            a0 = dot4(a0, w0, h0); a1 = dot4(a1, w1, h1);
            a2 = dot4(a2, w2, h2); a3 = dot4(a3, w3, h3);
            float a = (a0 + a1) + (a2 + a3);
            a = quad_add<0xB1>(a);   // + partner xor 1
            a = quad_add<0x4E>(a);   // + partner xor 2 -> full row dot in all 4 lanes
            if (q == 0) ghs[pb][u][sec] = a;

            lds_barrier();           // the only barrier per step (lgkm-only)

            // ---- redundant h-update on all waves (lane = hidden unit) ----
            const float4 gv = *reinterpret_cast<const float4*>(ghs[pb][lane]);
            const float r  = 1.0f / (1.0f + __expf(-(ir + gv.x)));
            const float z  = 1.0f / (1.0f + __expf(-(iz + gv.y)));
            const float aa = in_ + r * gv.z;
            const float e  = __expf(2.0f * aa);          // tanh(a) = 1 - 2/(e+1)
            const float n  = 1.0f - 2.0f / (e + 1.0f);
            const float hn = fmaf(z, h_prev - n, n);     // (1-z)*n + z*h
            h_prev = hn;
            hb[wv][lane] = hn;                           // own-wave copy
            if (wv == 0) sb[(size_t)t * Hv + lane] = hn; // fire-and-forget store
        }
    }
}

// out[i] = states[i,:] . W_out + b_out + x[i],  i in [0, B*T)
__global__ __launch_bounds__(256) void gru_head(
    const float* __restrict__ x,
    const float* __restrict__ states,
    const float* __restrict__ W_out,   // [64]
    const float* __restrict__ b_out,   // [1]
    float* __restrict__ out)
{
    __shared__ float wsm[Hv];
    if (threadIdx.x < Hv) wsm[threadIdx.x] = W_out[threadIdx.x];
    __syncthreads();

    const int i = blockIdx.x * blockDim.x + threadIdx.x;
    if (i >= Bv * Tv) return;

    const float4* s4 = reinterpret_cast<const float4*>(states + (size_t)i * Hv);
    float acc = 0.0f;
#pragma unroll
    for (int k = 0; k < Hv / 4; ++k) {
        const float4 v = s4[k];
        acc = fmaf(v.x, wsm[4*k+0], acc);
        acc = fmaf(v.y, wsm[4*k+1], acc);
        acc = fmaf(v.z, wsm[4*k+2], acc);
        acc = fmaf(v.w, wsm[4*k+3], acc);
    }
    out[i] = acc + b_out[0] + x[i];
}

extern "C" void kernel_launch(void* const* d_in, const int* in_sizes, int n_in,
                              void* d_out, int out_size, void* d_ws, size_t ws_size,
                              hipStream_t stream) {
    const float* x     = (const float*)d_in[0];   // [B,T,1]
    const float* W_ih  = (const float*)d_in[1];   // [192,1]
    const float* W_hh  = (const float*)d_in[2];   // [192,64]
    const float* b_ih  = (const float*)d_in[3];   // [192]
    const float* b_hh  = (const float*)d_in[4];   // [192]
    const float* W_out = (const float*)d_in[5];   // [1,64]
    const float* b_out = (const float*)d_in[6];   // [1]

    float* out    = (float*)d_out;                // [B*T]
    float* states = out + (size_t)Bv * Tv;        // [B*T*H]

    gru_scan<<<Bv, NT, 0, stream>>>(x, W_ih, W_hh, b_ih, b_hh, states);
    gru_head<<<(Bv * Tv + 255) / 256, 256, 0, stream>>>(x, states, W_out, b_out, out);
}